// Round 1
// baseline (2794.884 us; speedup 1.0000x reference)
//
#include <hip/hip_runtime.h>
#include <cstdint>
#include <cstddef>

typedef __bf16 bf16x8 __attribute__((ext_vector_type(8)));
typedef float f32x4 __attribute__((ext_vector_type(4)));
typedef int i32x4 __attribute__((ext_vector_type(4)));
typedef unsigned short u16;
typedef unsigned short u16x4 __attribute__((ext_vector_type(4)));

#define DEVI __device__ __forceinline__

namespace {

constexpr int kB = 16;
constexpr int kN = 2048;
constexpr int kD = 1024;
constexpr int kDepth = 6;
constexpr int kH = 16;
constexpr int kInner = 1024;
constexpr int kNL = 64;
constexpr int kFF = 4096;
constexpr int kTok = kN + kNL;  // 2112

constexpr int EPI_BF16 = 0, EPI_KV_X = 1, EPI_KV_L = 2, EPI_RES = 3,
              EPI_RES_BF = 4, EPI_GELU = 5, EPI_BIAS = 6;

DEVI u16 f2bf(float f) {
  unsigned u = __builtin_bit_cast(unsigned, f);
  return (u16)((u + 0x7fffu + ((u >> 16) & 1u)) >> 16);
}

// ---------------- LayerNorm (D=1024, one row per block, 256 thr) ----------------
template<bool OBF>
__global__ __launch_bounds__(256)
void ln_k(const float* __restrict__ in, const float* __restrict__ g,
          const float* __restrict__ b, void* __restrict__ out)
{
  const int row = blockIdx.x;
  const int tid = threadIdx.x;
  const f32x4 v = *(const f32x4*)(in + (size_t)row * kD + tid * 4);
  float s = v[0] + v[1] + v[2] + v[3];
  float ss = v[0]*v[0] + v[1]*v[1] + v[2]*v[2] + v[3]*v[3];
  #pragma unroll
  for (int off = 1; off < 64; off <<= 1) {
    s += __shfl_xor(s, off);
    ss += __shfl_xor(ss, off);
  }
  __shared__ float rs[4], rss[4];
  const int wv = tid >> 6;
  if ((tid & 63) == 0) { rs[wv] = s; rss[wv] = ss; }
  __syncthreads();
  s = rs[0] + rs[1] + rs[2] + rs[3];
  ss = rss[0] + rss[1] + rss[2] + rss[3];
  const float mean = s * (1.f / kD);
  const float var = ss * (1.f / kD) - mean * mean;
  const float rstd = rsqrtf(var + 1e-5f);
  float o[4];
  #pragma unroll
  for (int j = 0; j < 4; ++j) {
    const float gv = g ? g[tid * 4 + j] : 1.f;
    const float bv = b ? b[tid * 4 + j] : 0.f;
    o[j] = (v[j] - mean) * rstd * gv + bv;
  }
  if (OBF) {
    u16x4 pk;
    #pragma unroll
    for (int j = 0; j < 4; ++j) pk[j] = f2bf(o[j]);
    ((u16x4*)out)[(size_t)row * (kD / 4) + tid] = pk;
  } else {
    f32x4 pk = {o[0], o[1], o[2], o[3]};
    ((f32x4*)out)[(size_t)row * (kD / 4) + tid] = pk;
  }
}

// ---------------- f32 (L,K,N) -> bf16 (L,N,K) transpose+convert ----------------
__global__ __launch_bounds__(256)
void transpose_cvt(const float* __restrict__ in, u16* __restrict__ out,
                   int K, int N, const float* __restrict__ gscale, float cscale)
{
  __shared__ float tile[32][33];
  const int l = blockIdx.z;
  const int n0 = blockIdx.x * 32, k0 = blockIdx.y * 32;
  const int tx = threadIdx.x & 31, ty = threadIdx.x >> 5;
  const float* src = in + (size_t)l * K * N;
  #pragma unroll
  for (int i = 0; i < 32; i += 8) {
    const int k = k0 + ty + i;
    float v = src[(size_t)k * N + n0 + tx] * cscale;
    if (gscale) v *= gscale[(size_t)l * K + k];
    tile[ty + i][tx] = v;
  }
  __syncthreads();
  u16* dst = out + (size_t)l * K * N;
  #pragma unroll
  for (int i = 0; i < 32; i += 8) {
    const int n = n0 + ty + i;
    dst[(size_t)n * K + k0 + tx] = f2bf(tile[tx][ty + i]);
  }
}

// ---------------- bias_kv[l][j] = sum_d ln_media_b[l][d] * Wkv[l][d][j] ----------------
__global__ __launch_bounds__(256)
void biaskv_k(const float* __restrict__ bvec, const float* __restrict__ Wkv,
              float* __restrict__ bias)
{
  const int l = blockIdx.y;
  const int j = blockIdx.x * 256 + threadIdx.x;
  const float* w = Wkv + (size_t)l * kD * 2048 + j;
  const float* bb = bvec + (size_t)l * kD;
  float acc = 0.f;
  for (int d = 0; d < kD; ++d) acc = fmaf(bb[d], w[(size_t)d * 2048], acc);
  bias[(size_t)l * 2048 + j] = acc;
}

// ---------------- broadcast latents to (B,NL,D) f32 ----------------
__global__ __launch_bounds__(256)
void lat_init_k(const float* __restrict__ latents, float* __restrict__ lat)
{
  const int idx = blockIdx.x * 256 + threadIdx.x;   // f32x4 index
  const int per = kNL * kD / 4;                     // 16384 (pow2)
  ((f32x4*)lat)[idx] = ((const f32x4*)latents)[idx & (per - 1)];
}

// ---------------- GEMM: A(M,K) bf16 row-major  x  Bt(N,K) bf16 row-major ----------------
template<int ROWS>
DEVI void stage_tile(const u16* gbase, int ldk, char* lds, int wave, int lane) {
  constexpr int PW = ROWS / 32;     // 1KB calls per wave
  #pragma unroll
  for (int i = 0; i < PW; ++i) {
    const int c = wave * PW + i;
    const int row = c * 8 + (lane >> 3);
    const int cb = (lane & 7) * 16;
    const int scb = cb ^ ((row & 7) << 4);   // pre-swizzled source (LDS stays linear)
    const char* src = (const char*)(gbase + (size_t)row * ldk) + scb;
    __builtin_amdgcn_global_load_lds(
        (__attribute__((address_space(1))) void*)src,
        (__attribute__((address_space(3))) void*)(lds + c * 1024),
        16, 0, 0);
  }
}

template<int BM, int BN, int WM, int WN, int EPI>
__global__ __launch_bounds__(256, 2)
void gemm_k(const u16* __restrict__ A, const u16* __restrict__ Bt, int K, int N,
            const float* bias, const float* resid,
            float* outf, u16* outb, u16* kout, u16* vtout)
{
  constexpr int WTM = BM / WM, WTN = BN / WN;
  constexpr int FM = WTM / 16, FN = WTN / 16;
  __shared__ char lds_a[BM * 128];
  __shared__ char lds_b[BN * 128];
  const int tid = threadIdx.x;
  const int wave = tid >> 6, lane = tid & 63;
  const int l15 = lane & 15, l4 = lane >> 4;
  const int wr = wave / WN, wc = wave % WN;
  const int bm = blockIdx.y * BM, bn = blockIdx.x * BN;
  const u16* Ab = A + (size_t)bm * K;
  const u16* Bb = Bt + (size_t)bn * K;
  f32x4 acc[FM][FN] = {};
  for (int k0 = 0; k0 < K; k0 += 64) {
    stage_tile<BM>(Ab + k0, K, lds_a, wave, lane);
    stage_tile<BN>(Bb + k0, K, lds_b, wave, lane);
    __syncthreads();
    #pragma unroll
    for (int kk = 0; kk < 2; ++kk) {
      bf16x8 af[FM], bfr[FN];
      #pragma unroll
      for (int m = 0; m < FM; ++m) {
        const int row = wr * WTM + m * 16 + l15;
        const int cb = kk * 64 + l4 * 16;
        af[m] = *(const bf16x8*)(lds_a + row * 128 + (cb ^ ((row & 7) << 4)));
      }
      #pragma unroll
      for (int n = 0; n < FN; ++n) {
        const int row = wc * WTN + n * 16 + l15;
        const int cb = kk * 64 + l4 * 16;
        bfr[n] = *(const bf16x8*)(lds_b + row * 128 + (cb ^ ((row & 7) << 4)));
      }
      #pragma unroll
      for (int m = 0; m < FM; ++m)
        #pragma unroll
        for (int n = 0; n < FN; ++n)
          acc[m][n] = __builtin_amdgcn_mfma_f32_16x16x32_bf16(af[m], bfr[n], acc[m][n], 0, 0, 0);
    }
    __syncthreads();
  }
  #pragma unroll
  for (int m = 0; m < FM; ++m) {
    #pragma unroll
    for (int n = 0; n < FN; ++n) {
      const int r = bm + wr * WTM + m * 16 + l4 * 4;
      const int c = bn + wc * WTN + n * 16 + l15;
      f32x4 v = acc[m][n];
      if constexpr (EPI == EPI_BF16) {
        #pragma unroll
        for (int j = 0; j < 4; ++j) outb[(size_t)(r + j) * N + c] = f2bf(v[j]);
      } else if constexpr (EPI == EPI_GELU) {
        #pragma unroll
        for (int j = 0; j < 4; ++j) {
          const float x = v[j];
          outb[(size_t)(r + j) * N + c] = f2bf(0.5f * x * (1.f + erff(x * 0.7071067811865475f)));
        }
      } else if constexpr (EPI == EPI_RES || EPI == EPI_RES_BF) {
        #pragma unroll
        for (int j = 0; j < 4; ++j) {
          const float x = v[j] + resid[(size_t)(r + j) * N + c];
          outf[(size_t)(r + j) * N + c] = x;
          if constexpr (EPI == EPI_RES_BF) outb[(size_t)(r + j) * N + c] = f2bf(x);
        }
      } else if constexpr (EPI == EPI_BIAS) {
        #pragma unroll
        for (int j = 0; j < 4; ++j) outf[(size_t)(r + j) * N + c] = v[j] + bias[c];
      } else {  // KV epilogues: K half -> Kbuf[b][t][c]; V half -> VT[b][c-1024][t]
        int bb, t;
        float bv = 0.f;
        if constexpr (EPI == EPI_KV_X) { bb = r >> 11; t = r & 2047; bv = bias[c]; }
        else                           { bb = r >> 6;  t = 2048 + (r & 63); }
        if (c < kInner) {
          #pragma unroll
          for (int j = 0; j < 4; ++j)
            kout[((size_t)bb * kTok + t + j) * kInner + c] = f2bf(v[j] + bv);
        } else {
          u16x4 pk;
          #pragma unroll
          for (int j = 0; j < 4; ++j) pk[j] = f2bf(v[j] + bv);
          *(u16x4*)(vtout + ((size_t)bb * kInner + (c - kInner)) * kTok + t) = pk;
        }
      }
    }
  }
}

// ---------------- fused masked flash attention, one block per (b,h) ----------------
__global__ __launch_bounds__(256)
void attn_k(const u16* __restrict__ Kb, const u16* __restrict__ VT,
            const u16* __restrict__ Q, const int* __restrict__ mask,
            u16* __restrict__ O)
{
  const int bh = blockIdx.x;
  const int b = bh >> 4, h = bh & 15;
  const int tid = threadIdx.x;
  const int wave = tid >> 6, lane = tid & 63;
  const int l15 = lane & 15, l4 = lane >> 4;

  __shared__ char p_lds[4][64 * 128];        // per-wave P tile (q rows x 64 keys, swizzled)
  __shared__ float o_sm[64 * 65];            // [q][dh] padded merge buffer
  __shared__ float red_m[4][64], red_l[4][64], lstar[64];

  // Q fragments (B operand of S^T): col=q, k=dims
  bf16x8 qf[4][2];
  #pragma unroll
  for (int n = 0; n < 4; ++n)
    #pragma unroll
    for (int kk = 0; kk < 2; ++kk)
      qf[n][kk] = *(const bf16x8*)(Q + (size_t)(b * kNL + n * 16 + l15) * kInner + h * 64 + kk * 32 + 8 * l4);

  f32x4 oacc[4][4] = {};   // O^T frags: [m=dh frag][n=q frag]
  float mst[4], lst[4];
  #pragma unroll
  for (int n = 0; n < 4; ++n) { mst[n] = -1e30f; lst[n] = 0.f; }

  char* pw = p_lds[wave];

  for (int t = wave; t < 33; t += 4) {       // 33 key tiles of 64 (tile 32 = latents)
    const int key0 = t * 64;
    // S^T = K @ Q^T
    f32x4 s[4][4] = {};
    #pragma unroll
    for (int kk = 0; kk < 2; ++kk) {
      bf16x8 kf[4];
      #pragma unroll
      for (int m = 0; m < 4; ++m)
        kf[m] = *(const bf16x8*)(Kb + ((size_t)b * kTok + key0 + m * 16 + l15) * kInner + h * 64 + kk * 32 + 8 * l4);
      #pragma unroll
      for (int m = 0; m < 4; ++m)
        #pragma unroll
        for (int n = 0; n < 4; ++n)
          s[m][n] = __builtin_amdgcn_mfma_f32_16x16x32_bf16(kf[m], qf[n][kk], s[m][n], 0, 0, 0);
    }
    // validity per [m][reg]: keys key0 + m*16 + l4*4 + reg
    bool vld[4][4];
    if (t < 32) {
      #pragma unroll
      for (int m = 0; m < 4; ++m) {
        const i32x4 mk = *(const i32x4*)(mask + (size_t)b * kN + key0 + m * 16 + l4 * 4);
        #pragma unroll
        for (int j = 0; j < 4; ++j) vld[m][j] = (mk[j] != 0);
      }
    } else {
      #pragma unroll
      for (int m = 0; m < 4; ++m)
        #pragma unroll
        for (int j = 0; j < 4; ++j) vld[m][j] = true;
    }
    // online softmax per query column (n); reduce over l>>4 groups via shfl
    #pragma unroll
    for (int n = 0; n < 4; ++n) {
      float tm = -1e30f;
      #pragma unroll
      for (int m = 0; m < 4; ++m)
        #pragma unroll
        for (int j = 0; j < 4; ++j)
          tm = fmaxf(tm, vld[m][j] ? s[m][n][j] : -1e30f);
      tm = fmaxf(tm, __shfl_xor(tm, 16));
      tm = fmaxf(tm, __shfl_xor(tm, 32));
      const float mnew = fmaxf(mst[n], tm);
      const float sc = __expf(mst[n] - mnew);
      mst[n] = mnew;
      float rsum = 0.f;
      #pragma unroll
      for (int m = 0; m < 4; ++m)
        #pragma unroll
        for (int j = 0; j < 4; ++j) {
          const float pv = vld[m][j] ? __expf(s[m][n][j] - mnew) : 0.f;
          s[m][n][j] = pv;
          rsum += pv;
        }
      rsum += __shfl_xor(rsum, 16);
      rsum += __shfl_xor(rsum, 32);
      lst[n] = lst[n] * sc + rsum;
      #pragma unroll
      for (int m = 0; m < 4; ++m) oacc[m][n] *= sc;
    }
    // pack P into LDS: p_lds[q][key], 4 keys per lane per frag (b64, swizzled)
    #pragma unroll
    for (int m = 0; m < 4; ++m)
      #pragma unroll
      for (int n = 0; n < 4; ++n) {
        const int q = n * 16 + l15;
        const int kb = (m * 16 + l4 * 4) * 2;
        u16x4 pk;
        #pragma unroll
        for (int j = 0; j < 4; ++j) pk[j] = f2bf(s[m][n][j]);
        *(u16x4*)(pw + q * 128 + (kb ^ ((q & 7) << 4))) = pk;
      }
    // PV: O^T += V^T @ P^T
    #pragma unroll
    for (int kk = 0; kk < 2; ++kk) {
      bf16x8 vf[4], pf[4];
      #pragma unroll
      for (int m = 0; m < 4; ++m)
        vf[m] = *(const bf16x8*)(VT + ((size_t)b * kInner + h * 64 + m * 16 + l15) * kTok + key0 + kk * 32 + 8 * l4);
      #pragma unroll
      for (int n = 0; n < 4; ++n) {
        const int q = n * 16 + l15;
        const int cb = kk * 64 + l4 * 16;
        pf[n] = *(const bf16x8*)(pw + q * 128 + (cb ^ ((q & 7) << 4)));
      }
      #pragma unroll
      for (int m = 0; m < 4; ++m)
        #pragma unroll
        for (int n = 0; n < 4; ++n)
          oacc[m][n] = __builtin_amdgcn_mfma_f32_16x16x32_bf16(vf[m], pf[n], oacc[m][n], 0, 0, 0);
    }
  }

  // merge the 4 waves' partial (m, l, O)
  if (l4 == 0) {
    #pragma unroll
    for (int n = 0; n < 4; ++n) {
      red_m[wave][n * 16 + l15] = mst[n];
      red_l[wave][n * 16 + l15] = lst[n];
    }
  }
  __syncthreads();
  float coef[4];
  #pragma unroll
  for (int n = 0; n < 4; ++n) {
    const int q = n * 16 + l15;
    const float m0 = red_m[0][q], m1 = red_m[1][q], m2 = red_m[2][q], m3 = red_m[3][q];
    const float msx = fmaxf(fmaxf(m0, m1), fmaxf(m2, m3));
    coef[n] = __expf(mst[n] - msx);
    if (wave == 0 && l4 == 0)
      lstar[q] = red_l[0][q] * __expf(m0 - msx) + red_l[1][q] * __expf(m1 - msx)
               + red_l[2][q] * __expf(m2 - msx) + red_l[3][q] * __expf(m3 - msx);
  }
  #pragma unroll
  for (int m = 0; m < 4; ++m)
    #pragma unroll
    for (int n = 0; n < 4; ++n)
      oacc[m][n] *= coef[n];
  for (int w = 0; w < 4; ++w) {
    if (wave == w) {
      #pragma unroll
      for (int m = 0; m < 4; ++m)
        #pragma unroll
        for (int n = 0; n < 4; ++n) {
          const int q = n * 16 + l15;
          #pragma unroll
          for (int j = 0; j < 4; ++j) {
            const int dh = m * 16 + l4 * 4 + j;
            if (w == 0) o_sm[q * 65 + dh] = oacc[m][n][j];
            else        o_sm[q * 65 + dh] += oacc[m][n][j];
          }
        }
    }
    __syncthreads();
  }
  for (int i = tid; i < 64 * 64; i += 256) {
    const int q = i >> 6, dh = i & 63;
    O[(size_t)(b * kNL + q) * kInner + h * 64 + dh] = f2bf(o_sm[q * 65 + dh] / lstar[q]);
  }
}

}  // namespace

extern "C" void kernel_launch(void* const* d_in, const int* in_sizes, int n_in,
                              void* d_out, int out_size, void* d_ws, size_t ws_size,
                              hipStream_t stream)
{
  (void)in_sizes; (void)n_in; (void)out_size; (void)ws_size;
  const float* embeds  = (const float*)d_in[0];
  const float* latents = (const float*)d_in[1];
  const float* Wq    = (const float*)d_in[2];
  const float* Wkv   = (const float*)d_in[3];
  const float* Wo    = (const float*)d_in[4];
  const float* W1    = (const float*)d_in[5];
  const float* W2    = (const float*)d_in[6];
  const float* lmg   = (const float*)d_in[7];
  const float* lmb   = (const float*)d_in[8];
  const float* llg   = (const float*)d_in[9];
  const float* llb   = (const float*)d_in[10];
  const float* ffg   = (const float*)d_in[11];
  const float* ffbv  = (const float*)d_in[12];
  const float* projW = (const float*)d_in[13];
  const float* projB = (const float*)d_in[14];
  const float* fing  = (const float*)d_in[15];
  const float* finb  = (const float*)d_in[16];
  const int*   mask  = (const int*)d_in[17];
  float* out = (float*)d_out;

  char* p = (char*)d_ws;
  auto alloc = [&](size_t bytes) -> char* {
    char* r = p; p += (bytes + 255) & ~(size_t)255; return r;
  };
  u16* WqT   = (u16*)alloc((size_t)kDepth * kInner * kD * 2);
  u16* WkvT  = (u16*)alloc((size_t)kDepth * 2048 * kD * 2);
  u16* WkvfT = (u16*)alloc((size_t)kDepth * 2048 * kD * 2);
  u16* WoT   = (u16*)alloc((size_t)kDepth * kD * kInner * 2);
  u16* W1T   = (u16*)alloc((size_t)kDepth * kFF * kD * 2);
  u16* W2T   = (u16*)alloc((size_t)kDepth * kD * kFF * 2);
  u16* projT = (u16*)alloc((size_t)kD * kD * 2);
  float* bkv = (float*)alloc((size_t)kDepth * 2048 * 4);
  u16* xhat  = (u16*)alloc((size_t)kB * kN * kD * 2);
  u16* Kb    = (u16*)alloc((size_t)kB * kTok * kInner * 2);
  u16* VTb   = (u16*)alloc((size_t)kB * kInner * kTok * 2);
  u16* qb    = (u16*)alloc((size_t)kB * kNL * kInner * 2);
  u16* lln   = (u16*)alloc((size_t)kB * kNL * kD * 2);
  u16* ob    = (u16*)alloc((size_t)kB * kNL * kInner * 2);
  float* lat = (float*)alloc((size_t)kB * kNL * kD * 4);
  u16* latb  = (u16*)alloc((size_t)kB * kNL * kD * 2);
  u16* hb    = (u16*)alloc((size_t)kB * kNL * kD * 2);
  u16* ffbuf = (u16*)alloc((size_t)kB * kNL * kFF * 2);
  float* tmpo = (float*)alloc((size_t)kB * kNL * kD * 4);

  const dim3 blk(256);

  // one-time precompute (re-done every call; harness re-poisons ws)
  transpose_cvt<<<dim3(kInner/32, kD/32, kDepth), blk, 0, stream>>>(Wq, WqT, kD, kInner, nullptr, 0.125f);
  transpose_cvt<<<dim3(2048/32, kD/32, kDepth), blk, 0, stream>>>(Wkv, WkvT, kD, 2048, nullptr, 1.f);
  transpose_cvt<<<dim3(2048/32, kD/32, kDepth), blk, 0, stream>>>(Wkv, WkvfT, kD, 2048, lmg, 1.f);
  transpose_cvt<<<dim3(kD/32, kInner/32, kDepth), blk, 0, stream>>>(Wo, WoT, kInner, kD, nullptr, 1.f);
  transpose_cvt<<<dim3(kFF/32, kD/32, kDepth), blk, 0, stream>>>(W1, W1T, kD, kFF, nullptr, 1.f);
  transpose_cvt<<<dim3(kD/32, kFF/32, kDepth), blk, 0, stream>>>(W2, W2T, kFF, kD, nullptr, 1.f);
  transpose_cvt<<<dim3(kD/32, kD/32, 1), blk, 0, stream>>>(projW, projT, kD, kD, nullptr, 1.f);
  biaskv_k<<<dim3(8, kDepth), blk, 0, stream>>>(lmb, Wkv, bkv);
  ln_k<true><<<dim3(kB * kN), blk, 0, stream>>>(embeds, nullptr, nullptr, xhat);
  lat_init_k<<<dim3(kB * kNL * kD / 4 / 256), blk, 0, stream>>>(latents, lat);

  for (int i = 0; i < kDepth; ++i) {
    const u16* WqTi   = WqT   + (size_t)i * kInner * kD;
    const u16* WkvTi  = WkvT  + (size_t)i * 2048 * kD;
    const u16* WkvfTi = WkvfT + (size_t)i * 2048 * kD;
    const u16* WoTi   = WoT   + (size_t)i * kD * kInner;
    const u16* W1Ti   = W1T   + (size_t)i * kFF * kD;
    const u16* W2Ti   = W2T   + (size_t)i * kD * kFF;
    const float* bkvi = bkv   + (size_t)i * 2048;

    ln_k<true><<<dim3(kB * kNL), blk, 0, stream>>>(lat, llg + i * kD, llb + i * kD, lln);
    gemm_k<64,128,1,4,EPI_BF16><<<dim3(kInner/128, kB*kNL/64), blk, 0, stream>>>(
        lln, WqTi, kD, kInner, nullptr, nullptr, nullptr, qb, nullptr, nullptr);
    gemm_k<64,128,1,4,EPI_KV_L><<<dim3(2048/128, kB*kNL/64), blk, 0, stream>>>(
        lln, WkvTi, kD, 2048, nullptr, nullptr, nullptr, nullptr, Kb, VTb);
    gemm_k<128,128,2,2,EPI_KV_X><<<dim3(2048/128, kB*kN/128), blk, 0, stream>>>(
        xhat, WkvfTi, kD, 2048, bkvi, nullptr, nullptr, nullptr, Kb, VTb);
    attn_k<<<dim3(kB * kH), blk, 0, stream>>>(Kb, VTb, qb, mask, ob);
    gemm_k<64,128,1,4,EPI_RES><<<dim3(kD/128, kB*kNL/64), blk, 0, stream>>>(
        ob, WoTi, kInner, kD, nullptr, lat, lat, nullptr, nullptr, nullptr);
    ln_k<true><<<dim3(kB * kNL), blk, 0, stream>>>(lat, ffg + i * kD, ffbv + i * kD, hb);
    gemm_k<64,128,1,4,EPI_GELU><<<dim3(kFF/128, kB*kNL/64), blk, 0, stream>>>(
        hb, W1Ti, kD, kFF, nullptr, nullptr, nullptr, ffbuf, nullptr, nullptr);
    gemm_k<64,128,1,4,EPI_RES_BF><<<dim3(kD/128, kB*kNL/64), blk, 0, stream>>>(
        ffbuf, W2Ti, kFF, kD, nullptr, lat, lat, latb, nullptr, nullptr);
  }
  gemm_k<64,128,1,4,EPI_BIAS><<<dim3(kD/128, kB*kNL/64), blk, 0, stream>>>(
      latb, projT, kD, kD, projB, nullptr, tmpo, nullptr, nullptr, nullptr);
  ln_k<false><<<dim3(kB * kNL), blk, 0, stream>>>(tmpo, fing, finb, out);
}

// Round 2
// 2060.347 us; speedup vs baseline: 1.3565x; 1.3565x over previous
//
#include <hip/hip_runtime.h>
#include <cstdint>
#include <cstddef>

typedef __bf16 bf16x8 __attribute__((ext_vector_type(8)));
typedef float f32x4 __attribute__((ext_vector_type(4)));
typedef int i32x4 __attribute__((ext_vector_type(4)));
typedef unsigned short u16;
typedef unsigned short u16x4 __attribute__((ext_vector_type(4)));

#define DEVI __device__ __forceinline__

namespace {

constexpr int kB = 16;
constexpr int kN = 2048;
constexpr int kD = 1024;
constexpr int kDepth = 6;
constexpr int kH = 16;
constexpr int kInner = 1024;
constexpr int kNL = 64;
constexpr int kFF = 4096;
constexpr int kTok = kN + kNL;  // 2112

constexpr int EPI_BF16 = 0, EPI_KV_X = 1, EPI_KV_L = 2, EPI_RES = 3,
              EPI_RES_BF = 4, EPI_GELU = 5, EPI_BIAS = 6;

DEVI u16 f2bf(float f) {
  unsigned u = __builtin_bit_cast(unsigned, f);
  return (u16)((u + 0x7fffu + ((u >> 16) & 1u)) >> 16);
}
DEVI float bf2f(u16 u) { return __builtin_bit_cast(float, (unsigned)u << 16); }

// ---------------- per-batch mask compaction: pos list + counts ----------------
__global__ __launch_bounds__(256)
void compact_k(const int* __restrict__ mask, int* __restrict__ pos,
               int* __restrict__ cnt, int* __restrict__ cpad)
{
  const int b = blockIdx.x;
  const int tid = threadIdx.x;
  __shared__ int warp_tot[4];
  const int* mb = mask + (size_t)b * kN;
  int v[8]; int loc = 0;
  #pragma unroll
  for (int j = 0; j < 8; ++j) { v[j] = (mb[tid * 8 + j] != 0); loc += v[j]; }
  int pre = loc;
  #pragma unroll
  for (int off = 1; off < 64; off <<= 1) {
    int t = __shfl_up(pre, off);
    if ((tid & 63) >= off) pre += t;
  }
  if ((tid & 63) == 63) warp_tot[tid >> 6] = pre;
  __syncthreads();
  int wbase = 0;
  for (int w = 0; w < (tid >> 6); ++w) wbase += warp_tot[w];
  const int total = warp_tot[0] + warp_tot[1] + warp_tot[2] + warp_tot[3];
  int idx = wbase + pre - loc;
  int* pb = pos + (size_t)b * kN;
  #pragma unroll
  for (int j = 0; j < 8; ++j)
    if (v[j]) pb[idx++] = tid * 8 + j;
  if (tid == 0) { cnt[b] = total; cpad[b] = (total + 127) & ~127; }
}

// ---------------- LayerNorm (D=1024, one row per block, 256 thr) ----------------
template<bool OBF>
__global__ __launch_bounds__(256)
void ln_k(const float* __restrict__ in, const float* __restrict__ g,
          const float* __restrict__ b, void* __restrict__ out)
{
  const int row = blockIdx.x;
  const int tid = threadIdx.x;
  const f32x4 v = *(const f32x4*)(in + (size_t)row * kD + tid * 4);
  float s = v[0] + v[1] + v[2] + v[3];
  float ss = v[0]*v[0] + v[1]*v[1] + v[2]*v[2] + v[3]*v[3];
  #pragma unroll
  for (int off = 1; off < 64; off <<= 1) {
    s += __shfl_xor(s, off);
    ss += __shfl_xor(ss, off);
  }
  __shared__ float rs[4], rss[4];
  const int wv = tid >> 6;
  if ((tid & 63) == 0) { rs[wv] = s; rss[wv] = ss; }
  __syncthreads();
  s = rs[0] + rs[1] + rs[2] + rs[3];
  ss = rss[0] + rss[1] + rss[2] + rss[3];
  const float mean = s * (1.f / kD);
  const float var = ss * (1.f / kD) - mean * mean;
  const float rstd = rsqrtf(var + 1e-5f);
  float o[4];
  #pragma unroll
  for (int j = 0; j < 4; ++j) {
    const float gv = g ? g[tid * 4 + j] : 1.f;
    const float bv = b ? b[tid * 4 + j] : 0.f;
    o[j] = (v[j] - mean) * rstd * gv + bv;
  }
  if (OBF) {
    u16x4 pk;
    #pragma unroll
    for (int j = 0; j < 4; ++j) pk[j] = f2bf(o[j]);
    ((u16x4*)out)[(size_t)row * (kD / 4) + tid] = pk;
  } else {
    f32x4 pk = {o[0], o[1], o[2], o[3]};
    ((f32x4*)out)[(size_t)row * (kD / 4) + tid] = pk;
  }
}

// ---------------- LN of embeds, gathered into compacted slots ----------------
__global__ __launch_bounds__(256)
void ln_gather_k(const float* __restrict__ embeds, const int* __restrict__ pos,
                 const int* __restrict__ cnt, const int* __restrict__ cpad,
                 u16* __restrict__ xhat)
{
  const int b = blockIdx.y;
  const int s = blockIdx.x;
  const int tid = threadIdx.x;
  const int cv = cnt[b], cp = cpad[b];
  if (s >= cp) return;
  u16x4* dst = (u16x4*)(xhat + ((size_t)b * kN + s) * kD) + tid;
  if (s >= cv) { u16x4 z = {0, 0, 0, 0}; *dst = z; return; }
  const int row = pos[(size_t)b * kN + s];
  const f32x4 v = *(const f32x4*)(embeds + ((size_t)b * kN + row) * kD + tid * 4);
  float sm = v[0] + v[1] + v[2] + v[3];
  float ss = v[0]*v[0] + v[1]*v[1] + v[2]*v[2] + v[3]*v[3];
  #pragma unroll
  for (int off = 1; off < 64; off <<= 1) {
    sm += __shfl_xor(sm, off);
    ss += __shfl_xor(ss, off);
  }
  __shared__ float rs[4], rss[4];
  const int wv = tid >> 6;
  if ((tid & 63) == 0) { rs[wv] = sm; rss[wv] = ss; }
  __syncthreads();
  sm = rs[0] + rs[1] + rs[2] + rs[3];
  ss = rss[0] + rss[1] + rss[2] + rss[3];
  const float mean = sm * (1.f / kD);
  const float var = ss * (1.f / kD) - mean * mean;
  const float rstd = rsqrtf(var + 1e-5f);
  u16x4 pk;
  #pragma unroll
  for (int j = 0; j < 4; ++j) pk[j] = f2bf((v[j] - mean) * rstd);
  *dst = pk;
}

// ---------------- f32 (L,K,N) -> bf16 (L,N,K) transpose+convert ----------------
__global__ __launch_bounds__(256)
void transpose_cvt(const float* __restrict__ in, u16* __restrict__ out,
                   int K, int N, const float* __restrict__ gscale, float cscale)
{
  __shared__ float tile[32][33];
  const int l = blockIdx.z;
  const int n0 = blockIdx.x * 32, k0 = blockIdx.y * 32;
  const int tx = threadIdx.x & 31, ty = threadIdx.x >> 5;
  const float* src = in + (size_t)l * K * N;
  #pragma unroll
  for (int i = 0; i < 32; i += 8) {
    const int k = k0 + ty + i;
    float v = src[(size_t)k * N + n0 + tx] * cscale;
    if (gscale) v *= gscale[(size_t)l * K + k];
    tile[ty + i][tx] = v;
  }
  __syncthreads();
  u16* dst = out + (size_t)l * K * N;
  #pragma unroll
  for (int i = 0; i < 32; i += 8) {
    const int n = n0 + ty + i;
    dst[(size_t)n * K + k0 + tx] = f2bf(tile[tx][ty + i]);
  }
}

// ---------------- bias_kv[l][j] = dot(WkvT[l][j][:], ln_media_b[l][:]) ----------------
__global__ __launch_bounds__(256)
void biaskv_k(const float* __restrict__ bvec, const u16* __restrict__ WkvT,
              float* __restrict__ bias)
{
  const int l = blockIdx.y;
  const int j = blockIdx.x * 4 + (threadIdx.x >> 6);
  const int lane = threadIdx.x & 63;
  const u16* w = WkvT + ((size_t)l * 2048 + j) * kD + lane * 16;
  const float* bb = bvec + (size_t)l * kD + lane * 16;
  float acc = 0.f;
  #pragma unroll
  for (int i = 0; i < 16; ++i) acc = fmaf(bf2f(w[i]), bb[i], acc);
  #pragma unroll
  for (int off = 1; off < 64; off <<= 1) acc += __shfl_xor(acc, off);
  if (lane == 0) bias[(size_t)l * 2048 + j] = acc;
}

// ---------------- broadcast latents to (B,NL,D) f32 ----------------
__global__ __launch_bounds__(256)
void lat_init_k(const float* __restrict__ latents, float* __restrict__ lat)
{
  const int idx = blockIdx.x * 256 + threadIdx.x;
  const int per = kNL * kD / 4;
  ((f32x4*)lat)[idx] = ((const f32x4*)latents)[idx & (per - 1)];
}

// ---------------- GEMM: A(M,K) bf16 row-major  x  Bt(N,K) bf16 row-major ----------------
template<int ROWS>
DEVI void stage_tile(const u16* gbase, int ldk, char* lds, int wave, int lane) {
  constexpr int PW = ROWS / 32;
  #pragma unroll
  for (int i = 0; i < PW; ++i) {
    const int c = wave * PW + i;
    const int row = c * 8 + (lane >> 3);
    const int cb = (lane & 7) * 16;
    const int scb = cb ^ ((row & 7) << 4);
    const char* src = (const char*)(gbase + (size_t)row * ldk) + scb;
    __builtin_amdgcn_global_load_lds(
        (__attribute__((address_space(1))) void*)src,
        (__attribute__((address_space(3))) void*)(lds + c * 1024),
        16, 0, 0);
  }
}

template<int BM, int BN, int WM, int WN, int EPI>
__global__ __launch_bounds__(256, 2)
void gemm_k(const u16* __restrict__ A, const u16* __restrict__ Bt, int K, int N,
            const float* bias, const float* resid, const int* cpad,
            float* outf, u16* outb, u16* kout, u16* vtout)
{
  constexpr int WTM = BM / WM, WTN = BN / WN;
  constexpr int FM = WTM / 16, FN = WTN / 16;
  __shared__ char lds_a[BM * 128];
  __shared__ char lds_b[BN * 128];
  const int tid = threadIdx.x;
  const int wave = tid >> 6, lane = tid & 63;
  const int l15 = lane & 15, l4 = lane >> 4;
  const int wr = wave / WN, wc = wave % WN;
  const int bm = blockIdx.y * BM, bn = blockIdx.x * BN;

  if constexpr (EPI == EPI_KV_X) {
    if ((bm & (kN - 1)) >= cpad[bm >> 11]) return;   // fully-padded tile: skip
  }
  int tbase = 0;
  if constexpr (EPI == EPI_KV_L) tbase = cpad[bm >> 6];

  const u16* Ab = A + (size_t)bm * K;
  const u16* Bb = Bt + (size_t)bn * K;
  f32x4 acc[FM][FN] = {};
  for (int k0 = 0; k0 < K; k0 += 64) {
    stage_tile<BM>(Ab + k0, K, lds_a, wave, lane);
    stage_tile<BN>(Bb + k0, K, lds_b, wave, lane);
    __syncthreads();
    #pragma unroll
    for (int kk = 0; kk < 2; ++kk) {
      bf16x8 af[FM], bfr[FN];
      #pragma unroll
      for (int m = 0; m < FM; ++m) {
        const int row = wr * WTM + m * 16 + l15;
        const int cb = kk * 64 + l4 * 16;
        af[m] = *(const bf16x8*)(lds_a + row * 128 + (cb ^ ((row & 7) << 4)));
      }
      #pragma unroll
      for (int n = 0; n < FN; ++n) {
        const int row = wc * WTN + n * 16 + l15;
        const int cb = kk * 64 + l4 * 16;
        bfr[n] = *(const bf16x8*)(lds_b + row * 128 + (cb ^ ((row & 7) << 4)));
      }
      #pragma unroll
      for (int m = 0; m < FM; ++m)
        #pragma unroll
        for (int n = 0; n < FN; ++n)
          acc[m][n] = __builtin_amdgcn_mfma_f32_16x16x32_bf16(af[m], bfr[n], acc[m][n], 0, 0, 0);
    }
    __syncthreads();
  }
  #pragma unroll
  for (int m = 0; m < FM; ++m) {
    #pragma unroll
    for (int n = 0; n < FN; ++n) {
      const int r = bm + wr * WTM + m * 16 + l4 * 4;
      const int c = bn + wc * WTN + n * 16 + l15;
      f32x4 v = acc[m][n];
      if constexpr (EPI == EPI_BF16) {
        #pragma unroll
        for (int j = 0; j < 4; ++j) outb[(size_t)(r + j) * N + c] = f2bf(v[j]);
      } else if constexpr (EPI == EPI_GELU) {
        #pragma unroll
        for (int j = 0; j < 4; ++j) {
          const float x = v[j];
          outb[(size_t)(r + j) * N + c] = f2bf(0.5f * x * (1.f + erff(x * 0.7071067811865475f)));
        }
      } else if constexpr (EPI == EPI_RES || EPI == EPI_RES_BF) {
        #pragma unroll
        for (int j = 0; j < 4; ++j) {
          const float x = v[j] + resid[(size_t)(r + j) * N + c];
          outf[(size_t)(r + j) * N + c] = x;
          if constexpr (EPI == EPI_RES_BF) outb[(size_t)(r + j) * N + c] = f2bf(x);
        }
      } else if constexpr (EPI == EPI_BIAS) {
        #pragma unroll
        for (int j = 0; j < 4; ++j) outf[(size_t)(r + j) * N + c] = v[j] + bias[c];
      } else {  // KV epilogues
        int bb, t;
        float bv = 0.f;
        if constexpr (EPI == EPI_KV_X) { bb = r >> 11; t = r & (kN - 1); bv = bias[c]; }
        else                           { bb = r >> 6;  t = tbase + (r & 63); }
        if (c < kInner) {
          #pragma unroll
          for (int j = 0; j < 4; ++j)
            kout[((size_t)bb * kTok + t + j) * kInner + c] = f2bf(v[j] + bv);
        } else {
          u16x4 pk;
          #pragma unroll
          for (int j = 0; j < 4; ++j) pk[j] = f2bf(v[j] + bv);
          *(u16x4*)(vtout + ((size_t)bb * kInner + (c - kInner)) * kTok + t) = pk;
        }
      }
    }
  }
}

// ---------------- fused masked flash attention over compacted slots ----------------
__global__ __launch_bounds__(256)
void attn_k(const u16* __restrict__ Kb, const u16* __restrict__ VT,
            const u16* __restrict__ Q, const int* __restrict__ cnt,
            const int* __restrict__ cpad, u16* __restrict__ O)
{
  const int bh = blockIdx.x;
  const int b = bh >> 4, h = bh & 15;
  const int tid = threadIdx.x;
  const int wave = tid >> 6, lane = tid & 63;
  const int l15 = lane & 15, l4 = lane >> 4;
  const int cv = cnt[b], cp = cpad[b];
  const int nt = (cp >> 6) + 1;   // media tiles + 1 latent tile (at slot cp)

  __shared__ char p_lds[4][64 * 128];
  __shared__ float o_sm[64 * 65];
  __shared__ float red_m[4][64], red_l[4][64], lstar[64];

  bf16x8 qf[4][2];
  #pragma unroll
  for (int n = 0; n < 4; ++n)
    #pragma unroll
    for (int kk = 0; kk < 2; ++kk)
      qf[n][kk] = *(const bf16x8*)(Q + (size_t)(b * kNL + n * 16 + l15) * kInner + h * 64 + kk * 32 + 8 * l4);

  f32x4 oacc[4][4] = {};
  float mst[4], lst[4];
  #pragma unroll
  for (int n = 0; n < 4; ++n) { mst[n] = -1e30f; lst[n] = 0.f; }

  char* pw = p_lds[wave];

  for (int t = wave; t < nt; t += 4) {
    const int key0 = t * 64;
    const bool isLat = (t == nt - 1);
    f32x4 s[4][4] = {};
    #pragma unroll
    for (int kk = 0; kk < 2; ++kk) {
      bf16x8 kf[4];
      #pragma unroll
      for (int m = 0; m < 4; ++m)
        kf[m] = *(const bf16x8*)(Kb + ((size_t)b * kTok + key0 + m * 16 + l15) * kInner + h * 64 + kk * 32 + 8 * l4);
      #pragma unroll
      for (int m = 0; m < 4; ++m)
        #pragma unroll
        for (int n = 0; n < 4; ++n)
          s[m][n] = __builtin_amdgcn_mfma_f32_16x16x32_bf16(kf[m], qf[n][kk], s[m][n], 0, 0, 0);
    }
    const bool allv = isLat || (key0 + 64 <= cv);
    bool vld[4][4];
    #pragma unroll
    for (int m = 0; m < 4; ++m)
      #pragma unroll
      for (int j = 0; j < 4; ++j)
        vld[m][j] = allv || (key0 + m * 16 + l4 * 4 + j < cv);
    #pragma unroll
    for (int n = 0; n < 4; ++n) {
      float tm = -1e30f;
      #pragma unroll
      for (int m = 0; m < 4; ++m)
        #pragma unroll
        for (int j = 0; j < 4; ++j)
          tm = fmaxf(tm, vld[m][j] ? s[m][n][j] : -1e30f);
      tm = fmaxf(tm, __shfl_xor(tm, 16));
      tm = fmaxf(tm, __shfl_xor(tm, 32));
      const float mnew = fmaxf(mst[n], tm);
      const float sc = __expf(mst[n] - mnew);
      mst[n] = mnew;
      float rsum = 0.f;
      #pragma unroll
      for (int m = 0; m < 4; ++m)
        #pragma unroll
        for (int j = 0; j < 4; ++j) {
          const float pv = vld[m][j] ? __expf(s[m][n][j] - mnew) : 0.f;
          s[m][n][j] = pv;
          rsum += pv;
        }
      rsum += __shfl_xor(rsum, 16);
      rsum += __shfl_xor(rsum, 32);
      lst[n] = lst[n] * sc + rsum;
      #pragma unroll
      for (int m = 0; m < 4; ++m) oacc[m][n] *= sc;
    }
    #pragma unroll
    for (int m = 0; m < 4; ++m)
      #pragma unroll
      for (int n = 0; n < 4; ++n) {
        const int q = n * 16 + l15;
        const int kb = (m * 16 + l4 * 4) * 2;
        u16x4 pk;
        #pragma unroll
        for (int j = 0; j < 4; ++j) pk[j] = f2bf(s[m][n][j]);
        *(u16x4*)(pw + q * 128 + (kb ^ ((q & 7) << 4))) = pk;
      }
    #pragma unroll
    for (int kk = 0; kk < 2; ++kk) {
      bf16x8 vf[4], pf[4];
      #pragma unroll
      for (int m = 0; m < 4; ++m)
        vf[m] = *(const bf16x8*)(VT + ((size_t)b * kInner + h * 64 + m * 16 + l15) * kTok + key0 + kk * 32 + 8 * l4);
      #pragma unroll
      for (int n = 0; n < 4; ++n) {
        const int q = n * 16 + l15;
        const int cb = kk * 64 + l4 * 16;
        pf[n] = *(const bf16x8*)(pw + q * 128 + (cb ^ ((q & 7) << 4)));
      }
      #pragma unroll
      for (int m = 0; m < 4; ++m)
        #pragma unroll
        for (int n = 0; n < 4; ++n)
          oacc[m][n] = __builtin_amdgcn_mfma_f32_16x16x32_bf16(vf[m], pf[n], oacc[m][n], 0, 0, 0);
    }
  }

  if (l4 == 0) {
    #pragma unroll
    for (int n = 0; n < 4; ++n) {
      red_m[wave][n * 16 + l15] = mst[n];
      red_l[wave][n * 16 + l15] = lst[n];
    }
  }
  __syncthreads();
  float coef[4];
  #pragma unroll
  for (int n = 0; n < 4; ++n) {
    const int q = n * 16 + l15;
    const float m0 = red_m[0][q], m1 = red_m[1][q], m2 = red_m[2][q], m3 = red_m[3][q];
    const float msx = fmaxf(fmaxf(m0, m1), fmaxf(m2, m3));
    coef[n] = __expf(mst[n] - msx);
    if (wave == 0 && l4 == 0)
      lstar[q] = red_l[0][q] * __expf(m0 - msx) + red_l[1][q] * __expf(m1 - msx)
               + red_l[2][q] * __expf(m2 - msx) + red_l[3][q] * __expf(m3 - msx);
  }
  #pragma unroll
  for (int m = 0; m < 4; ++m)
    #pragma unroll
    for (int n = 0; n < 4; ++n)
      oacc[m][n] *= coef[n];
  for (int w = 0; w < 4; ++w) {
    if (wave == w) {
      #pragma unroll
      for (int m = 0; m < 4; ++m)
        #pragma unroll
        for (int n = 0; n < 4; ++n) {
          const int q = n * 16 + l15;
          #pragma unroll
          for (int j = 0; j < 4; ++j) {
            const int dh = m * 16 + l4 * 4 + j;
            if (w == 0) o_sm[q * 65 + dh] = oacc[m][n][j];
            else        o_sm[q * 65 + dh] += oacc[m][n][j];
          }
        }
    }
    __syncthreads();
  }
  for (int i = tid; i < 64 * 64; i += 256) {
    const int q = i >> 6, dh = i & 63;
    O[(size_t)(b * kNL + q) * kInner + h * 64 + dh] = f2bf(o_sm[q * 65 + dh] / lstar[q]);
  }
}

}  // namespace

extern "C" void kernel_launch(void* const* d_in, const int* in_sizes, int n_in,
                              void* d_out, int out_size, void* d_ws, size_t ws_size,
                              hipStream_t stream)
{
  (void)in_sizes; (void)n_in; (void)out_size; (void)ws_size;
  const float* embeds  = (const float*)d_in[0];
  const float* latents = (const float*)d_in[1];
  const float* Wq    = (const float*)d_in[2];
  const float* Wkv   = (const float*)d_in[3];
  const float* Wo    = (const float*)d_in[4];
  const float* W1    = (const float*)d_in[5];
  const float* W2    = (const float*)d_in[6];
  const float* lmg   = (const float*)d_in[7];
  const float* lmb   = (const float*)d_in[8];
  const float* llg   = (const float*)d_in[9];
  const float* llb   = (const float*)d_in[10];
  const float* ffg   = (const float*)d_in[11];
  const float* ffbv  = (const float*)d_in[12];
  const float* projW = (const float*)d_in[13];
  const float* projB = (const float*)d_in[14];
  const float* fing  = (const float*)d_in[15];
  const float* finb  = (const float*)d_in[16];
  const int*   mask  = (const int*)d_in[17];
  float* out = (float*)d_out;

  char* p = (char*)d_ws;
  auto alloc = [&](size_t bytes) -> char* {
    char* r = p; p += (bytes + 255) & ~(size_t)255; return r;
  };
  u16* WqT   = (u16*)alloc((size_t)kDepth * kInner * kD * 2);
  u16* WkvT  = (u16*)alloc((size_t)kDepth * 2048 * kD * 2);
  u16* WkvfT = (u16*)alloc((size_t)kDepth * 2048 * kD * 2);
  u16* WoT   = (u16*)alloc((size_t)kDepth * kD * kInner * 2);
  u16* W1T   = (u16*)alloc((size_t)kDepth * kFF * kD * 2);
  u16* W2T   = (u16*)alloc((size_t)kDepth * kD * kFF * 2);
  u16* projT = (u16*)alloc((size_t)kD * kD * 2);
  float* bkv = (float*)alloc((size_t)kDepth * 2048 * 4);
  u16* xhat  = (u16*)alloc((size_t)kB * kN * kD * 2);
  u16* Kb    = (u16*)alloc((size_t)kB * kTok * kInner * 2);
  u16* VTb   = (u16*)alloc((size_t)kB * kInner * kTok * 2);
  u16* qb    = (u16*)alloc((size_t)kB * kNL * kInner * 2);
  u16* lln   = (u16*)alloc((size_t)kB * kNL * kD * 2);
  u16* ob    = (u16*)alloc((size_t)kB * kNL * kInner * 2);
  float* lat = (float*)alloc((size_t)kB * kNL * kD * 4);
  u16* latb  = (u16*)alloc((size_t)kB * kNL * kD * 2);
  u16* hb    = (u16*)alloc((size_t)kB * kNL * kD * 2);
  u16* ffbuf = (u16*)alloc((size_t)kB * kNL * kFF * 2);
  float* tmpo = (float*)alloc((size_t)kB * kNL * kD * 4);
  int* pos  = (int*)alloc((size_t)kB * kN * 4);
  int* cnt  = (int*)alloc(kB * 4);
  int* cpad = (int*)alloc(kB * 4);

  const dim3 blk(256);

  compact_k<<<dim3(kB), blk, 0, stream>>>(mask, pos, cnt, cpad);
  transpose_cvt<<<dim3(kInner/32, kD/32, kDepth), blk, 0, stream>>>(Wq, WqT, kD, kInner, nullptr, 0.125f);
  transpose_cvt<<<dim3(2048/32, kD/32, kDepth), blk, 0, stream>>>(Wkv, WkvT, kD, 2048, nullptr, 1.f);
  transpose_cvt<<<dim3(2048/32, kD/32, kDepth), blk, 0, stream>>>(Wkv, WkvfT, kD, 2048, lmg, 1.f);
  transpose_cvt<<<dim3(kD/32, kInner/32, kDepth), blk, 0, stream>>>(Wo, WoT, kInner, kD, nullptr, 1.f);
  transpose_cvt<<<dim3(kFF/32, kD/32, kDepth), blk, 0, stream>>>(W1, W1T, kD, kFF, nullptr, 1.f);
  transpose_cvt<<<dim3(kD/32, kFF/32, kDepth), blk, 0, stream>>>(W2, W2T, kFF, kD, nullptr, 1.f);
  transpose_cvt<<<dim3(kD/32, kD/32, 1), blk, 0, stream>>>(projW, projT, kD, kD, nullptr, 1.f);
  biaskv_k<<<dim3(512, kDepth), blk, 0, stream>>>(lmb, WkvT, bkv);
  ln_gather_k<<<dim3(kN, kB), blk, 0, stream>>>(embeds, pos, cnt, cpad, xhat);
  lat_init_k<<<dim3(kB * kNL * kD / 4 / 256), blk, 0, stream>>>(latents, lat);

  for (int i = 0; i < kDepth; ++i) {
    const u16* WqTi   = WqT   + (size_t)i * kInner * kD;
    const u16* WkvTi  = WkvT  + (size_t)i * 2048 * kD;
    const u16* WkvfTi = WkvfT + (size_t)i * 2048 * kD;
    const u16* WoTi   = WoT   + (size_t)i * kD * kInner;
    const u16* W1Ti   = W1T   + (size_t)i * kFF * kD;
    const u16* W2Ti   = W2T   + (size_t)i * kD * kFF;
    const float* bkvi = bkv   + (size_t)i * 2048;

    ln_k<true><<<dim3(kB * kNL), blk, 0, stream>>>(lat, llg + i * kD, llb + i * kD, lln);
    gemm_k<64,64,2,2,EPI_BF16><<<dim3(kInner/64, kB*kNL/64), blk, 0, stream>>>(
        lln, WqTi, kD, kInner, nullptr, nullptr, nullptr, nullptr, qb, nullptr, nullptr);
    gemm_k<64,64,2,2,EPI_KV_L><<<dim3(2048/64, kB*kNL/64), blk, 0, stream>>>(
        lln, WkvTi, kD, 2048, nullptr, nullptr, cpad, nullptr, nullptr, Kb, VTb);
    gemm_k<128,128,2,2,EPI_KV_X><<<dim3(2048/128, kB*kN/128), blk, 0, stream>>>(
        xhat, WkvfTi, kD, 2048, bkvi, nullptr, cpad, nullptr, nullptr, Kb, VTb);
    attn_k<<<dim3(kB * kH), blk, 0, stream>>>(Kb, VTb, qb, cnt, cpad, ob);
    gemm_k<64,64,2,2,EPI_RES><<<dim3(kD/64, kB*kNL/64), blk, 0, stream>>>(
        ob, WoTi, kInner, kD, nullptr, lat, nullptr, lat, nullptr, nullptr, nullptr);
    ln_k<true><<<dim3(kB * kNL), blk, 0, stream>>>(lat, ffg + i * kD, ffbv + i * kD, hb);
    gemm_k<64,64,2,2,EPI_GELU><<<dim3(kFF/64, kB*kNL/64), blk, 0, stream>>>(
        hb, W1Ti, kD, kFF, nullptr, nullptr, nullptr, nullptr, ffbuf, nullptr, nullptr);
    gemm_k<64,64,2,2,EPI_RES_BF><<<dim3(kD/64, kB*kNL/64), blk, 0, stream>>>(
        ffbuf, W2Ti, kFF, kD, nullptr, lat, nullptr, lat, latb, nullptr, nullptr);
  }
  gemm_k<64,64,2,2,EPI_BIAS><<<dim3(kD/64, kB*kNL/64), blk, 0, stream>>>(
      latb, projT, kD, kD, projB, nullptr, nullptr, tmpo, nullptr, nullptr, nullptr);
  ln_k<false><<<dim3(kB * kNL), blk, 0, stream>>>(tmpo, fing, finb, out);
}

// Round 3
// 1812.105 us; speedup vs baseline: 1.5423x; 1.1370x over previous
//
#include <hip/hip_runtime.h>
#include <cstdint>
#include <cstddef>

typedef __bf16 bf16x8 __attribute__((ext_vector_type(8)));
typedef float f32x4 __attribute__((ext_vector_type(4)));
typedef unsigned short u16;
typedef unsigned short u16x4 __attribute__((ext_vector_type(4)));
typedef unsigned short u16x8 __attribute__((ext_vector_type(8)));

#define DEVI __device__ __forceinline__

namespace {

constexpr int kB = 16;
constexpr int kN = 2048;
constexpr int kD = 1024;
constexpr int kDepth = 6;
constexpr int kH = 16;
constexpr int kInner = 1024;
constexpr int kNL = 64;
constexpr int kFF = 4096;
constexpr int kTok = kN + kNL;  // 2112

constexpr int EPI_KV_X = 1, EPI_RES = 3, EPI_RES_BF = 4, EPI_GELU = 5,
              EPI_BIAS = 6, EPI_QKV = 7;

DEVI u16 f2bf(float f) {
  unsigned u = __builtin_bit_cast(unsigned, f);
  return (u16)((u + 0x7fffu + ((u >> 16) & 1u)) >> 16);
}
DEVI float bf2f(u16 u) { return __builtin_bit_cast(float, (unsigned)u << 16); }

// ---------------- per-batch mask compaction: pos list + counts ----------------
__global__ __launch_bounds__(256)
void compact_k(const int* __restrict__ mask, int* __restrict__ pos,
               int* __restrict__ cnt, int* __restrict__ cpad)
{
  const int b = blockIdx.x;
  const int tid = threadIdx.x;
  __shared__ int warp_tot[4];
  const int* mb = mask + (size_t)b * kN;
  int v[8]; int loc = 0;
  #pragma unroll
  for (int j = 0; j < 8; ++j) { v[j] = (mb[tid * 8 + j] != 0); loc += v[j]; }
  int pre = loc;
  #pragma unroll
  for (int off = 1; off < 64; off <<= 1) {
    int t = __shfl_up(pre, off);
    if ((tid & 63) >= off) pre += t;
  }
  if ((tid & 63) == 63) warp_tot[tid >> 6] = pre;
  __syncthreads();
  int wbase = 0;
  for (int w = 0; w < (tid >> 6); ++w) wbase += warp_tot[w];
  const int total = warp_tot[0] + warp_tot[1] + warp_tot[2] + warp_tot[3];
  int idx = wbase + pre - loc;
  int* pb = pos + (size_t)b * kN;
  #pragma unroll
  for (int j = 0; j < 8; ++j)
    if (v[j]) pb[idx++] = tid * 8 + j;
  if (tid == 0) { cnt[b] = total; cpad[b] = (total + 127) & ~127; }
}

// ---------------- LayerNorm (D=1024, one row per block, 256 thr) ----------------
template<bool OBF>
__global__ __launch_bounds__(256)
void ln_k(const float* __restrict__ in, const float* __restrict__ g,
          const float* __restrict__ b, void* __restrict__ out)
{
  const int row = blockIdx.x;
  const int tid = threadIdx.x;
  const f32x4 v = *(const f32x4*)(in + (size_t)row * kD + tid * 4);
  float s = v[0] + v[1] + v[2] + v[3];
  float ss = v[0]*v[0] + v[1]*v[1] + v[2]*v[2] + v[3]*v[3];
  #pragma unroll
  for (int off = 1; off < 64; off <<= 1) {
    s += __shfl_xor(s, off);
    ss += __shfl_xor(ss, off);
  }
  __shared__ float rs[4], rss[4];
  const int wv = tid >> 6;
  if ((tid & 63) == 0) { rs[wv] = s; rss[wv] = ss; }
  __syncthreads();
  s = rs[0] + rs[1] + rs[2] + rs[3];
  ss = rss[0] + rss[1] + rss[2] + rss[3];
  const float mean = s * (1.f / kD);
  const float var = ss * (1.f / kD) - mean * mean;
  const float rstd = rsqrtf(var + 1e-5f);
  float o[4];
  #pragma unroll
  for (int j = 0; j < 4; ++j) {
    const float gv = g ? g[tid * 4 + j] : 1.f;
    const float bv = b ? b[tid * 4 + j] : 0.f;
    o[j] = (v[j] - mean) * rstd * gv + bv;
  }
  if (OBF) {
    u16x4 pk;
    #pragma unroll
    for (int j = 0; j < 4; ++j) pk[j] = f2bf(o[j]);
    ((u16x4*)out)[(size_t)row * (kD / 4) + tid] = pk;
  } else {
    f32x4 pk = {o[0], o[1], o[2], o[3]};
    ((f32x4*)out)[(size_t)row * (kD / 4) + tid] = pk;
  }
}

// ---------------- LN of embeds, gathered into compacted slots ----------------
__global__ __launch_bounds__(256)
void ln_gather_k(const float* __restrict__ embeds, const int* __restrict__ pos,
                 const int* __restrict__ cnt, const int* __restrict__ cpad,
                 u16* __restrict__ xhat)
{
  const int b = blockIdx.y;
  const int s = blockIdx.x;
  const int tid = threadIdx.x;
  const int cv = cnt[b], cp = cpad[b];
  if (s >= cp) return;
  u16x4* dst = (u16x4*)(xhat + ((size_t)b * kN + s) * kD) + tid;
  if (s >= cv) { u16x4 z = {0, 0, 0, 0}; *dst = z; return; }
  const int row = pos[(size_t)b * kN + s];
  const f32x4 v = *(const f32x4*)(embeds + ((size_t)b * kN + row) * kD + tid * 4);
  float sm = v[0] + v[1] + v[2] + v[3];
  float ss = v[0]*v[0] + v[1]*v[1] + v[2]*v[2] + v[3]*v[3];
  #pragma unroll
  for (int off = 1; off < 64; off <<= 1) {
    sm += __shfl_xor(sm, off);
    ss += __shfl_xor(ss, off);
  }
  __shared__ float rs[4], rss[4];
  const int wv = tid >> 6;
  if ((tid & 63) == 0) { rs[wv] = sm; rss[wv] = ss; }
  __syncthreads();
  sm = rs[0] + rs[1] + rs[2] + rs[3];
  ss = rss[0] + rss[1] + rss[2] + rss[3];
  const float mean = sm * (1.f / kD);
  const float var = ss * (1.f / kD) - mean * mean;
  const float rstd = rsqrtf(var + 1e-5f);
  u16x4 pk;
  #pragma unroll
  for (int j = 0; j < 4; ++j) pk[j] = f2bf((v[j] - mean) * rstd);
  *dst = pk;
}

// ---------------- f32 (L,K,N) -> bf16 (L, coff+N, K) transpose+convert ----------------
__global__ __launch_bounds__(256)
void transpose_cvt(const float* __restrict__ in, u16* __restrict__ out,
                   int K, int N, size_t ldo, int coff, float cscale)
{
  __shared__ float tile[32][33];
  const int l = blockIdx.z;
  const int n0 = blockIdx.x * 32, k0 = blockIdx.y * 32;
  const int tx = threadIdx.x & 31, ty = threadIdx.x >> 5;
  const float* src = in + (size_t)l * K * N;
  #pragma unroll
  for (int i = 0; i < 32; i += 8)
    tile[ty + i][tx] = src[(size_t)(k0 + ty + i) * N + n0 + tx] * cscale;
  __syncthreads();
  u16* dst = out + (size_t)l * ldo;
  #pragma unroll
  for (int i = 0; i < 32; i += 8) {
    const int n = n0 + ty + i;
    dst[(size_t)(coff + n) * K + k0 + tx] = f2bf(tile[tx][ty + i]);
  }
}

// ---------------- Wkv dual transpose: plain -> WqkvT cols 1024.., g-folded -> WkvfT ----------------
__global__ __launch_bounds__(256)
void transpose_kv(const float* __restrict__ in, u16* __restrict__ out_plain,
                  u16* __restrict__ out_fold, const float* __restrict__ gvec)
{
  __shared__ float tile[32][33];
  const int l = blockIdx.z;
  const int n0 = blockIdx.x * 32, k0 = blockIdx.y * 32;
  const int tx = threadIdx.x & 31, ty = threadIdx.x >> 5;
  const float* src = in + (size_t)l * kD * 2048;
  #pragma unroll
  for (int i = 0; i < 32; i += 8)
    tile[ty + i][tx] = src[(size_t)(k0 + ty + i) * 2048 + n0 + tx];
  __syncthreads();
  const float gv = gvec[(size_t)l * kD + k0 + tx];
  u16* dp = out_plain + (size_t)l * (3072 * kD);
  u16* df = out_fold + (size_t)l * (2048 * kD);
  #pragma unroll
  for (int i = 0; i < 32; i += 8) {
    const int n = n0 + ty + i;
    const float v = tile[tx][ty + i];
    dp[(size_t)(1024 + n) * kD + k0 + tx] = f2bf(v);
    df[(size_t)n * kD + k0 + tx] = f2bf(v * gv);
  }
}

// ---------------- bias_kv[l][j] = dot(WkvT_plain[l][j][:], ln_media_b[l][:]) ----------------
__global__ __launch_bounds__(256)
void biaskv_k(const float* __restrict__ bvec, const u16* __restrict__ WqkvT,
              float* __restrict__ bias)
{
  const int l = blockIdx.y;
  const int j = blockIdx.x * 4 + (threadIdx.x >> 6);
  const int lane = threadIdx.x & 63;
  const u16* w = WqkvT + (size_t)l * (3072 * kD) + (size_t)(1024 + j) * kD + lane * 16;
  const float* bb = bvec + (size_t)l * kD + lane * 16;
  float acc = 0.f;
  #pragma unroll
  for (int i = 0; i < 16; ++i) acc = fmaf(bf2f(w[i]), bb[i], acc);
  #pragma unroll
  for (int off = 1; off < 64; off <<= 1) acc += __shfl_xor(acc, off);
  if (lane == 0) bias[(size_t)l * 2048 + j] = acc;
}

// ---------------- broadcast latents to (B,NL,D) f32 ----------------
__global__ __launch_bounds__(256)
void lat_init_k(const float* __restrict__ latents, float* __restrict__ lat)
{
  const int idx = blockIdx.x * 256 + threadIdx.x;
  const int per = kNL * kD / 4;
  ((f32x4*)lat)[idx] = ((const f32x4*)latents)[idx & (per - 1)];
}

// ---------------- GEMM: A(M,K) bf16 row-major  x  Bt(N,K) bf16 row-major ----------------
template<int ROWS>
DEVI void stage_tile(const u16* gbase, int ldk, char* lds, int wave, int lane) {
  constexpr int PW = ROWS / 32;
  #pragma unroll
  for (int i = 0; i < PW; ++i) {
    const int c = wave * PW + i;
    const int row = c * 8 + (lane >> 3);
    const int cb = (lane & 7) * 16;
    const int scb = cb ^ ((row & 7) << 4);
    const char* src = (const char*)(gbase + (size_t)row * ldk) + scb;
    __builtin_amdgcn_global_load_lds(
        (__attribute__((address_space(1))) void*)src,
        (__attribute__((address_space(3))) void*)(lds + c * 1024),
        16, 0, 0);
  }
}

template<int BM, int BN, int WM, int WN, int EPI>
__global__ __launch_bounds__(256, 2)
void gemm_k(const u16* __restrict__ A, const u16* __restrict__ Bt, int K, int N,
            const float* bias, const float* resid, const int* cpad,
            float* outf, u16* outb, u16* kout, u16* vtout)
{
  constexpr int WTM = BM / WM, WTN = BN / WN;
  constexpr int FM = WTM / 16, FN = WTN / 16;
  __shared__ char lds_raw[(BM + BN) * 128];
  char* lds_a = lds_raw;
  char* lds_b = lds_raw + BM * 128;
  const int tid = threadIdx.x;
  const int wave = tid >> 6, lane = tid & 63;
  const int l15 = lane & 15, l4 = lane >> 4;
  const int wr = wave / WN, wc = wave % WN;
  const int bm = blockIdx.y * BM, bn = blockIdx.x * BN;

  if constexpr (EPI == EPI_KV_X) {
    if ((bm & (kN - 1)) >= cpad[bm >> 11]) return;   // fully-padded tile: skip
  }
  int tbase = 0;
  if constexpr (EPI == EPI_QKV) tbase = cpad[bm >> 6];

  const u16* Ab = A + (size_t)bm * K;
  const u16* Bb = Bt + (size_t)bn * K;
  f32x4 acc[FM][FN] = {};
  for (int k0 = 0; k0 < K; k0 += 64) {
    stage_tile<BM>(Ab + k0, K, lds_a, wave, lane);
    stage_tile<BN>(Bb + k0, K, lds_b, wave, lane);
    __syncthreads();
    #pragma unroll
    for (int kk = 0; kk < 2; ++kk) {
      bf16x8 af[FM], bfr[FN];
      #pragma unroll
      for (int m = 0; m < FM; ++m) {
        const int row = wr * WTM + m * 16 + l15;
        const int cb = kk * 64 + l4 * 16;
        af[m] = *(const bf16x8*)(lds_a + row * 128 + (cb ^ ((row & 7) << 4)));
      }
      #pragma unroll
      for (int n = 0; n < FN; ++n) {
        const int row = wc * WTN + n * 16 + l15;
        const int cb = kk * 64 + l4 * 16;
        bfr[n] = *(const bf16x8*)(lds_b + row * 128 + (cb ^ ((row & 7) << 4)));
      }
      #pragma unroll
      for (int m = 0; m < FM; ++m)
        #pragma unroll
        for (int n = 0; n < FN; ++n)
          acc[m][n] = __builtin_amdgcn_mfma_f32_16x16x32_bf16(af[m], bfr[n], acc[m][n], 0, 0, 0);
    }
    __syncthreads();
  }

  if constexpr (EPI == EPI_KV_X) {
    const int bb = bm >> 11;
    const int tloc = bm & (kN - 1);
    if (bn >= kInner) {
      // ---- V half: restage through LDS -> contiguous 16B stores along t ----
      #pragma unroll
      for (int m = 0; m < FM; ++m)
        #pragma unroll
        for (int n = 0; n < FN; ++n) {
          const int rl = wr * WTM + m * 16 + l4 * 4;
          const int cl = wc * WTN + n * 16 + l15;
          const float bv = bias[bn + cl];
          u16x4 pk;
          #pragma unroll
          for (int j = 0; j < 4; ++j) pk[j] = f2bf(acc[m][n][j] + bv);
          *(u16x4*)(lds_raw + cl * 256 + ((rl * 2) ^ ((cl & 15) << 4))) = pk;
        }
      __syncthreads();
      #pragma unroll
      for (int it = 0; it < 8; ++it) {
        const int idx = it * 256 + tid;
        const int cl = idx >> 4, ch = idx & 15;
        const u16x8 val = *(const u16x8*)(lds_raw + cl * 256 + ((ch * 16) ^ ((cl & 15) << 4)));
        *(u16x8*)(vtout + ((size_t)bb * kInner + (bn - kInner) + cl) * kTok + tloc + ch * 8) = val;
      }
    } else {
      // ---- K half: direct (c-contiguous lines) ----
      #pragma unroll
      for (int m = 0; m < FM; ++m)
        #pragma unroll
        for (int n = 0; n < FN; ++n) {
          const int t = tloc + wr * WTM + m * 16 + l4 * 4;
          const int c = bn + wc * WTN + n * 16 + l15;
          const float bv = bias[c];
          #pragma unroll
          for (int j = 0; j < 4; ++j)
            kout[((size_t)bb * kTok + t + j) * kInner + c] = f2bf(acc[m][n][j] + bv);
        }
    }
    return;
  }

  #pragma unroll
  for (int m = 0; m < FM; ++m) {
    #pragma unroll
    for (int n = 0; n < FN; ++n) {
      const int r = bm + wr * WTM + m * 16 + l4 * 4;
      const int c = bn + wc * WTN + n * 16 + l15;
      f32x4 v = acc[m][n];
      if constexpr (EPI == EPI_GELU) {
        #pragma unroll
        for (int j = 0; j < 4; ++j) {
          const float x = v[j];
          outb[(size_t)(r + j) * N + c] = f2bf(0.5f * x * (1.f + erff(x * 0.7071067811865475f)));
        }
      } else if constexpr (EPI == EPI_RES || EPI == EPI_RES_BF) {
        #pragma unroll
        for (int j = 0; j < 4; ++j) {
          const float x = v[j] + resid[(size_t)(r + j) * N + c];
          outf[(size_t)(r + j) * N + c] = x;
          if constexpr (EPI == EPI_RES_BF) outb[(size_t)(r + j) * N + c] = f2bf(x);
        }
      } else if constexpr (EPI == EPI_BIAS) {
        #pragma unroll
        for (int j = 0; j < 4; ++j) outf[(size_t)(r + j) * N + c] = v[j] + bias[c];
      } else if constexpr (EPI == EPI_QKV) {
        const int bb = r >> 6;
        if (c < 1024) {
          #pragma unroll
          for (int j = 0; j < 4; ++j) outb[(size_t)(r + j) * kInner + c] = f2bf(v[j]);
        } else if (c < 2048) {
          #pragma unroll
          for (int j = 0; j < 4; ++j)
            kout[((size_t)bb * kTok + tbase + (r & 63) + j) * kInner + (c - 1024)] = f2bf(v[j]);
        } else {
          u16x4 pk;
          #pragma unroll
          for (int j = 0; j < 4; ++j) pk[j] = f2bf(v[j]);
          *(u16x4*)(vtout + ((size_t)bb * kInner + (c - 2048)) * kTok + tbase + (r & 63)) = pk;
        }
      }
    }
  }
}

// ---------------- fused masked flash attention over compacted slots ----------------
__global__ __launch_bounds__(256)
void attn_k(const u16* __restrict__ Kb, const u16* __restrict__ VT,
            const u16* __restrict__ Q, const int* __restrict__ cnt,
            const int* __restrict__ cpad, u16* __restrict__ O)
{
  const int bh = blockIdx.x;
  const int b = bh >> 4, h = bh & 15;
  const int tid = threadIdx.x;
  const int wave = tid >> 6, lane = tid & 63;
  const int l15 = lane & 15, l4 = lane >> 4;
  const int cv = cnt[b], cp = cpad[b];
  const int nt = (cp >> 6) + 1;   // media tiles + 1 latent tile (at slot cp)

  __shared__ char p_lds[4][64 * 128];
  __shared__ float o_sm[64 * 65];
  __shared__ float red_m[4][64], red_l[4][64], lstar[64];

  bf16x8 qf[4][2];
  #pragma unroll
  for (int n = 0; n < 4; ++n)
    #pragma unroll
    for (int kk = 0; kk < 2; ++kk)
      qf[n][kk] = *(const bf16x8*)(Q + (size_t)(b * kNL + n * 16 + l15) * kInner + h * 64 + kk * 32 + 8 * l4);

  f32x4 oacc[4][4] = {};
  float mst[4], lst[4];
  #pragma unroll
  for (int n = 0; n < 4; ++n) { mst[n] = -1e30f; lst[n] = 0.f; }

  char* pw = p_lds[wave];

  for (int t = wave; t < nt; t += 4) {
    const int key0 = t * 64;
    const bool isLat = (t == nt - 1);
    f32x4 s[4][4] = {};
    #pragma unroll
    for (int kk = 0; kk < 2; ++kk) {
      bf16x8 kf[4];
      #pragma unroll
      for (int m = 0; m < 4; ++m)
        kf[m] = *(const bf16x8*)(Kb + ((size_t)b * kTok + key0 + m * 16 + l15) * kInner + h * 64 + kk * 32 + 8 * l4);
      #pragma unroll
      for (int m = 0; m < 4; ++m)
        #pragma unroll
        for (int n = 0; n < 4; ++n)
          s[m][n] = __builtin_amdgcn_mfma_f32_16x16x32_bf16(kf[m], qf[n][kk], s[m][n], 0, 0, 0);
    }
    const bool allv = isLat || (key0 + 64 <= cv);
    bool vld[4][4];
    #pragma unroll
    for (int m = 0; m < 4; ++m)
      #pragma unroll
      for (int j = 0; j < 4; ++j)
        vld[m][j] = allv || (key0 + m * 16 + l4 * 4 + j < cv);
    #pragma unroll
    for (int n = 0; n < 4; ++n) {
      float tm = -1e30f;
      #pragma unroll
      for (int m = 0; m < 4; ++m)
        #pragma unroll
        for (int j = 0; j < 4; ++j)
          tm = fmaxf(tm, vld[m][j] ? s[m][n][j] : -1e30f);
      tm = fmaxf(tm, __shfl_xor(tm, 16));
      tm = fmaxf(tm, __shfl_xor(tm, 32));
      const float mnew = fmaxf(mst[n], tm);
      const float sc = __expf(mst[n] - mnew);
      mst[n] = mnew;
      float rsum = 0.f;
      #pragma unroll
      for (int m = 0; m < 4; ++m)
        #pragma unroll
        for (int j = 0; j < 4; ++j) {
          const float pv = vld[m][j] ? __expf(s[m][n][j] - mnew) : 0.f;
          s[m][n][j] = pv;
          rsum += pv;
        }
      rsum += __shfl_xor(rsum, 16);
      rsum += __shfl_xor(rsum, 32);
      lst[n] = lst[n] * sc + rsum;
      #pragma unroll
      for (int m = 0; m < 4; ++m) oacc[m][n] *= sc;
    }
    #pragma unroll
    for (int m = 0; m < 4; ++m)
      #pragma unroll
      for (int n = 0; n < 4; ++n) {
        const int q = n * 16 + l15;
        const int kb = (m * 16 + l4 * 4) * 2;
        u16x4 pk;
        #pragma unroll
        for (int j = 0; j < 4; ++j) pk[j] = f2bf(s[m][n][j]);
        *(u16x4*)(pw + q * 128 + (kb ^ ((q & 7) << 4))) = pk;
      }
    #pragma unroll
    for (int kk = 0; kk < 2; ++kk) {
      bf16x8 vf[4], pf[4];
      #pragma unroll
      for (int m = 0; m < 4; ++m)
        vf[m] = *(const bf16x8*)(VT + ((size_t)b * kInner + h * 64 + m * 16 + l15) * kTok + key0 + kk * 32 + 8 * l4);
      #pragma unroll
      for (int n = 0; n < 4; ++n) {
        const int q = n * 16 + l15;
        const int cb = kk * 64 + l4 * 16;
        pf[n] = *(const bf16x8*)(pw + q * 128 + (cb ^ ((q & 7) << 4)));
      }
      #pragma unroll
      for (int m = 0; m < 4; ++m)
        #pragma unroll
        for (int n = 0; n < 4; ++n)
          oacc[m][n] = __builtin_amdgcn_mfma_f32_16x16x32_bf16(vf[m], pf[n], oacc[m][n], 0, 0, 0);
    }
  }

  if (l4 == 0) {
    #pragma unroll
    for (int n = 0; n < 4; ++n) {
      red_m[wave][n * 16 + l15] = mst[n];
      red_l[wave][n * 16 + l15] = lst[n];
    }
  }
  __syncthreads();
  float coef[4];
  #pragma unroll
  for (int n = 0; n < 4; ++n) {
    const int q = n * 16 + l15;
    const float m0 = red_m[0][q], m1 = red_m[1][q], m2 = red_m[2][q], m3 = red_m[3][q];
    const float msx = fmaxf(fmaxf(m0, m1), fmaxf(m2, m3));
    coef[n] = __expf(mst[n] - msx);
    if (wave == 0 && l4 == 0)
      lstar[q] = red_l[0][q] * __expf(m0 - msx) + red_l[1][q] * __expf(m1 - msx)
               + red_l[2][q] * __expf(m2 - msx) + red_l[3][q] * __expf(m3 - msx);
  }
  #pragma unroll
  for (int m = 0; m < 4; ++m)
    #pragma unroll
    for (int n = 0; n < 4; ++n)
      oacc[m][n] *= coef[n];
  for (int w = 0; w < 4; ++w) {
    if (wave == w) {
      #pragma unroll
      for (int m = 0; m < 4; ++m)
        #pragma unroll
        for (int n = 0; n < 4; ++n) {
          const int q = n * 16 + l15;
          #pragma unroll
          for (int j = 0; j < 4; ++j) {
            const int dh = m * 16 + l4 * 4 + j;
            if (w == 0) o_sm[q * 65 + dh] = oacc[m][n][j];
            else        o_sm[q * 65 + dh] += oacc[m][n][j];
          }
        }
    }
    __syncthreads();
  }
  for (int i = tid; i < 64 * 64; i += 256) {
    const int q = i >> 6, dh = i & 63;
    O[(size_t)(b * kNL + q) * kInner + h * 64 + dh] = f2bf(o_sm[q * 65 + dh] / lstar[q]);
  }
}

}  // namespace

extern "C" void kernel_launch(void* const* d_in, const int* in_sizes, int n_in,
                              void* d_out, int out_size, void* d_ws, size_t ws_size,
                              hipStream_t stream)
{
  (void)in_sizes; (void)n_in; (void)out_size; (void)ws_size;
  const float* embeds  = (const float*)d_in[0];
  const float* latents = (const float*)d_in[1];
  const float* Wq    = (const float*)d_in[2];
  const float* Wkv   = (const float*)d_in[3];
  const float* Wo    = (const float*)d_in[4];
  const float* W1    = (const float*)d_in[5];
  const float* W2    = (const float*)d_in[6];
  const float* lmg   = (const float*)d_in[7];
  const float* lmb   = (const float*)d_in[8];
  const float* llg   = (const float*)d_in[9];
  const float* llb   = (const float*)d_in[10];
  const float* ffg   = (const float*)d_in[11];
  const float* ffbv  = (const float*)d_in[12];
  const float* projW = (const float*)d_in[13];
  const float* projB = (const float*)d_in[14];
  const float* fing  = (const float*)d_in[15];
  const float* finb  = (const float*)d_in[16];
  const int*   mask  = (const int*)d_in[17];
  float* out = (float*)d_out;

  char* p = (char*)d_ws;
  auto alloc = [&](size_t bytes) -> char* {
    char* r = p; p += (bytes + 255) & ~(size_t)255; return r;
  };
  u16* WqkvT = (u16*)alloc((size_t)kDepth * 3072 * kD * 2);
  u16* WkvfT = (u16*)alloc((size_t)kDepth * 2048 * kD * 2);
  u16* WoT   = (u16*)alloc((size_t)kDepth * kD * kInner * 2);
  u16* W1T   = (u16*)alloc((size_t)kDepth * kFF * kD * 2);
  u16* W2T   = (u16*)alloc((size_t)kDepth * kD * kFF * 2);
  u16* projT = (u16*)alloc((size_t)kD * kD * 2);
  float* bkv = (float*)alloc((size_t)kDepth * 2048 * 4);
  u16* xhat  = (u16*)alloc((size_t)kB * kN * kD * 2);
  u16* Kb    = (u16*)alloc((size_t)kB * kTok * kInner * 2);
  u16* VTb   = (u16*)alloc((size_t)kB * kInner * kTok * 2);
  u16* qb    = (u16*)alloc((size_t)kB * kNL * kInner * 2);
  u16* lln   = (u16*)alloc((size_t)kB * kNL * kD * 2);
  u16* ob    = (u16*)alloc((size_t)kB * kNL * kInner * 2);
  float* lat = (float*)alloc((size_t)kB * kNL * kD * 4);
  u16* latb  = (u16*)alloc((size_t)kB * kNL * kD * 2);
  u16* hb    = (u16*)alloc((size_t)kB * kNL * kD * 2);
  u16* ffbuf = (u16*)alloc((size_t)kB * kNL * kFF * 2);
  float* tmpo = (float*)alloc((size_t)kB * kNL * kD * 4);
  int* pos  = (int*)alloc((size_t)kB * kN * 4);
  int* cnt  = (int*)alloc(kB * 4);
  int* cpad = (int*)alloc(kB * 4);

  const dim3 blk(256);

  compact_k<<<dim3(kB), blk, 0, stream>>>(mask, pos, cnt, cpad);
  transpose_cvt<<<dim3(kInner/32, kD/32, kDepth), blk, 0, stream>>>(Wq, WqkvT, kD, kInner, (size_t)3072 * kD, 0, 0.125f);
  transpose_kv<<<dim3(2048/32, kD/32, kDepth), blk, 0, stream>>>(Wkv, WqkvT, WkvfT, lmg);
  transpose_cvt<<<dim3(kD/32, kInner/32, kDepth), blk, 0, stream>>>(Wo, WoT, kInner, kD, (size_t)kD * kInner, 0, 1.f);
  transpose_cvt<<<dim3(kFF/32, kD/32, kDepth), blk, 0, stream>>>(W1, W1T, kD, kFF, (size_t)kFF * kD, 0, 1.f);
  transpose_cvt<<<dim3(kD/32, kFF/32, kDepth), blk, 0, stream>>>(W2, W2T, kFF, kD, (size_t)kD * kFF, 0, 1.f);
  transpose_cvt<<<dim3(kD/32, kD/32, 1), blk, 0, stream>>>(projW, projT, kD, kD, (size_t)kD * kD, 0, 1.f);
  biaskv_k<<<dim3(512, kDepth), blk, 0, stream>>>(lmb, WqkvT, bkv);
  ln_gather_k<<<dim3(kN, kB), blk, 0, stream>>>(embeds, pos, cnt, cpad, xhat);
  lat_init_k<<<dim3(kB * kNL * kD / 4 / 256), blk, 0, stream>>>(latents, lat);

  for (int i = 0; i < kDepth; ++i) {
    const u16* WqkvTi = WqkvT + (size_t)i * 3072 * kD;
    const u16* WkvfTi = WkvfT + (size_t)i * 2048 * kD;
    const u16* WoTi   = WoT   + (size_t)i * kD * kInner;
    const u16* W1Ti   = W1T   + (size_t)i * kFF * kD;
    const u16* W2Ti   = W2T   + (size_t)i * kD * kFF;
    const float* bkvi = bkv   + (size_t)i * 2048;

    ln_k<true><<<dim3(kB * kNL), blk, 0, stream>>>(lat, llg + i * kD, llb + i * kD, lln);
    gemm_k<64,64,2,2,EPI_QKV><<<dim3(3072/64, kB*kNL/64), blk, 0, stream>>>(
        lln, WqkvTi, kD, 3072, nullptr, nullptr, cpad, nullptr, qb, Kb, VTb);
    gemm_k<128,128,2,2,EPI_KV_X><<<dim3(2048/128, kB*kN/128), blk, 0, stream>>>(
        xhat, WkvfTi, kD, 2048, bkvi, nullptr, cpad, nullptr, nullptr, Kb, VTb);
    attn_k<<<dim3(kB * kH), blk, 0, stream>>>(Kb, VTb, qb, cnt, cpad, ob);
    gemm_k<64,64,2,2,EPI_RES><<<dim3(kD/64, kB*kNL/64), blk, 0, stream>>>(
        ob, WoTi, kInner, kD, nullptr, lat, nullptr, lat, nullptr, nullptr, nullptr);
    ln_k<true><<<dim3(kB * kNL), blk, 0, stream>>>(lat, ffg + i * kD, ffbv + i * kD, hb);
    gemm_k<64,64,2,2,EPI_GELU><<<dim3(kFF/64, kB*kNL/64), blk, 0, stream>>>(
        hb, W1Ti, kD, kFF, nullptr, nullptr, nullptr, nullptr, ffbuf, nullptr, nullptr);
    gemm_k<64,64,2,2,EPI_RES_BF><<<dim3(kD/64, kB*kNL/64), blk, 0, stream>>>(
        ffbuf, W2Ti, kFF, kD, nullptr, lat, nullptr, lat, latb, nullptr, nullptr);
  }
  gemm_k<64,64,2,2,EPI_BIAS><<<dim3(kD/64, kB*kNL/64), blk, 0, stream>>>(
      latb, projT, kD, kD, projB, nullptr, nullptr, tmpo, nullptr, nullptr, nullptr);
  ln_k<false><<<dim3(kB * kNL), blk, 0, stream>>>(tmpo, fing, finb, out);
}